// Round 1
// baseline (9372.403 us; speedup 1.0000x reference)
//
#include <hip/hip_runtime.h>
#include <stdint.h>

// Autoregressive GRU  B=256, D=1024, T=128  — single persistent cooperative kernel.
// Design:
//  - grid 256 blocks (1/CU, cooperative), block = 4 waves; wave q = gate quarter
//    (z | r | Wh-path | Uh-path), block dt = 16 dims, rt = 64 rows.
//  - Weights M = [Wz+Uz | Wr+Ur | Wh | Uh] folded from f32 ONCE in the prologue:
//    bf16-hi fragments -> LDS (128 KB), bf16-lo fragments -> VGPRs (wlo[32], 128 regs).
//    Per-step B traffic is zero; no packed-weight workspace, no pack kernels.
//  - State h[t] double-buffered in ws as bf16 hi+lo (2 x 1 MB); h_prev f32 kept in
//    registers (4/thread). Per-step global traffic: A-frags (1 MB/CU via L1/L2) + stores.
//  - Step 0 (inp=0, h=x): gates = [x@Uz | x@Ur | 0 | x@Uh]; q3 reuses steady weights,
//    q0/q1 stream U f32 and split in-register, q2 skips (acc=0 -> xh=bias). Same
//    3-term split-bf16 MFMA precision as steady steps.
//  - Sync: rows are independent across dt, so each step only needs a 64-block barrier
//    per rt-group: per-(rt,t) counters (64B apart), release-add + relaxed spin +
//    acquire fence. Reads of state[t-1] always precede arrival at barrier t, so the
//    2-buffer rotation is race-free. Counters zeroed by hipMemsetAsync each launch.

#define DDIM    1024
#define THREE_D 3072
#define TSTEPS  128

typedef short bf16x8 __attribute__((ext_vector_type(8)));
typedef float f32x4  __attribute__((ext_vector_type(4)));

static __device__ __forceinline__ unsigned short f2bf(float f) {
    union { float f; uint32_t u; } v; v.f = f;
    uint32_t u = v.u;
    uint32_t r = u + 0x7FFFu + ((u >> 16) & 1u);   // round-to-nearest-even
    return (unsigned short)(r >> 16);
}
static __device__ __forceinline__ float bf2f(unsigned short h) {
    union { uint32_t u; float f; } v; v.u = ((uint32_t)h) << 16; return v.f;
}
static __device__ __forceinline__ void split8(const float* v, bf16x8& hi, bf16x8& lo) {
    #pragma unroll
    for (int j = 0; j < 8; ++j) {
        unsigned short h = f2bf(v[j]);
        hi[j] = (short)h;
        lo[j] = (short)f2bf(v[j] - bf2f(h));
    }
}

__global__ __launch_bounds__(256, 1) void gru_persistent(
    const float* __restrict__ x, const float* __restrict__ W,
    const float* __restrict__ U, const float* __restrict__ bias,
    float* __restrict__ out, unsigned short* __restrict__ hb,
    int* __restrict__ syncc)
{
    extern __shared__ char smem[];
    unsigned short* whi = (unsigned short*)smem;        // [4][32][64][8] shorts = 128 KB
    float* gbuf = (float*)(smem + 131072);              // [4][64][17] f32 = 17408 B (padded)

    const int tid  = threadIdx.x;
    const int lane = tid & 63;
    const int q    = tid >> 6;          // wave id == gate quarter
    const int dt   = blockIdx.x & 63;   // dim tile (16 dims)
    const int rt   = blockIdx.x >> 6;   // row tile (64 rows)
    const int llow = lane & 15;
    const int lhi  = lane >> 4;
    const int d    = dt * 16 + llow;    // B-fragment column (dim within gate)

    // ---- one-time: fold weights in f32, split to bf16 hi (LDS) + lo (VGPRs) ----
    // B-frag layout (proven in prior kernel): col = ntile*16+(lane&15),
    // k = kt*32 + (lane>>4)*8 + j
    bf16x8 wlo[32];
    {
        const int cc = (q == 0) ? d : (q == 1) ? (1024 + d) : (2048 + d);
        const float* m1 = (q == 3) ? U : W;
        #pragma unroll
        for (int kt = 0; kt < 32; ++kt) {
            float v[8];
            #pragma unroll
            for (int j = 0; j < 8; ++j) {
                int k = kt * 32 + lhi * 8 + j;
                float val = m1[(size_t)k * THREE_D + cc];
                if (q <= 1) val += U[(size_t)k * THREE_D + cc];
                v[j] = val;
            }
            bf16x8 bh, bl;
            split8(v, bh, bl);
            *(bf16x8*)(whi + ((q * 32 + kt) * 64 + lane) * 8) = bh;
            wlo[kt] = bl;
        }
    }

    // ---- epilogue constants (fixed per thread across all 128 steps) ----
    const int erow = tid >> 4;          // 0..15
    const int ecol = tid & 15;
    const int dd   = dt * 16 + ecol;
    const float bz = bias[dd];
    const float br = bias[1024 + dd];
    const float bx = bias[2048 + dd];
    size_t ooff[4], hoff[4];
    float hprev[4];
    #pragma unroll
    for (int i = 0; i < 4; ++i) {
        int grow = rt * 64 + erow + i * 16;
        ooff[i]  = (size_t)grow * (TSTEPS * DDIM) + dd;
        hoff[i]  = (size_t)grow * DDIM + dd;
        hprev[i] = x[(size_t)grow * DDIM + dd];     // h at step 0 is x
    }
    __syncthreads();

    // acc -> gbuf -> gates -> new h -> out + bf16 hi/lo state stores
    auto epilogue = [&](int t, f32x4* acc, unsigned short* dh, unsigned short* dl) {
        // C/D layout: col = lane&15, row = (lane>>4)*4 + reg  [measured m89]
        #pragma unroll
        for (int m = 0; m < 4; ++m)
            #pragma unroll
            for (int r = 0; r < 4; ++r)
                gbuf[(q * 64 + m * 16 + lhi * 4 + r) * 17 + llow] = acc[m][r];
        __syncthreads();
        #pragma unroll
        for (int i = 0; i < 4; ++i) {
            int row = erow + i * 16;
            float gz = gbuf[(0 * 64 + row) * 17 + ecol] + bz;
            float gr = gbuf[(1 * 64 + row) * 17 + ecol] + br;
            float gx = gbuf[(2 * 64 + row) * 17 + ecol] + bx;
            float gu = gbuf[(3 * 64 + row) * 17 + ecol];
            float z  = 1.0f / (1.0f + __expf(-gz));
            float r_ = 1.0f / (1.0f + __expf(-gr));
            float hh = tanhf(gx + r_ * gu);
            float hn = z * hprev[i] + (1.0f - z) * hh;
            hprev[i] = hn;
            out[ooff[i] + (size_t)t * DDIM] = hn;
            unsigned short hi = f2bf(hn);
            dh[hoff[i]] = hi;
            dl[hoff[i]] = f2bf(hn - bf2f(hi));
        }
    };

    // 64-block barrier per rt-group; per-(rt,t) counter, 64 B apart.
    auto barrier = [&](int t) {
        __threadfence();                 // release this thread's state stores (agent)
        __syncthreads();                 // all threads fenced
        if (tid == 0) {
            int* c = syncc + (t * 4 + rt) * 16;
            __hip_atomic_fetch_add(c, 1, __ATOMIC_RELEASE, __HIP_MEMORY_SCOPE_AGENT);
            while (__hip_atomic_load(c, __ATOMIC_RELAXED, __HIP_MEMORY_SCOPE_AGENT) < 64)
                __builtin_amdgcn_s_sleep(2);
            __threadfence();             // acquire: invalidate L1/L2 before state reads
        }
        __syncthreads();
    };

    const unsigned short* wbase = whi + ((q * 32) * 64 + lane) * 8;

    // ---- t = 0:  gates = [x@Uz | x@Ur | 0 | x@Uh] ----
    {
        f32x4 acc[4] = {f32x4{0,0,0,0}, f32x4{0,0,0,0}, f32x4{0,0,0,0}, f32x4{0,0,0,0}};
        if (q != 2) {
            const float* xb = x + (size_t)(rt * 64 + llow) * DDIM + lhi * 8;
            const float* ub = U + ((q == 0) ? d : (q == 1) ? (1024 + d) : (2048 + d));
            #pragma unroll
            for (int kt = 0; kt < 32; ++kt) {
                bf16x8 bh, bl;
                if (q == 3) {            // steady q3 weights ARE Uh
                    bh = *(const bf16x8*)(wbase + kt * 512);
                    bl = wlo[kt];
                } else {                 // stream Uz / Ur f32, split in-register
                    float v[8];
                    #pragma unroll
                    for (int j = 0; j < 8; ++j)
                        v[j] = ub[(size_t)(kt * 32 + lhi * 8 + j) * THREE_D];
                    split8(v, bh, bl);
                }
                #pragma unroll
                for (int m = 0; m < 4; ++m) {
                    float a[8];
                    const float* ap = xb + (size_t)m * 16 * DDIM + kt * 32;
                    #pragma unroll
                    for (int j = 0; j < 8; ++j) a[j] = ap[j];
                    bf16x8 ah, al;
                    split8(a, ah, al);
                    acc[m] = __builtin_amdgcn_mfma_f32_16x16x32_bf16(ah, bh, acc[m], 0, 0, 0);
                    acc[m] = __builtin_amdgcn_mfma_f32_16x16x32_bf16(al, bh, acc[m], 0, 0, 0);
                    acc[m] = __builtin_amdgcn_mfma_f32_16x16x32_bf16(ah, bl, acc[m], 0, 0, 0);
                }
            }
        }
        epilogue(0, acc, hb, hb + 262144);      // state[0] -> buf0
        barrier(0);
    }

    // ---- t = 1 .. 127: B from LDS/regs, A from double-buffered state ----
    for (int t = 1; t < TSTEPS; ++t) {
        const unsigned short* sh = hb + (size_t)((t - 1) & 1) * 524288;
        const unsigned short* sl = sh + 262144;
        unsigned short* dh = hb + (size_t)(t & 1) * 524288;
        unsigned short* dl = dh + 262144;
        const unsigned short* ahp = sh + (size_t)(rt * 64 + llow) * DDIM + lhi * 8;
        const unsigned short* alp = sl + (size_t)(rt * 64 + llow) * DDIM + lhi * 8;

        f32x4 acc[4] = {f32x4{0,0,0,0}, f32x4{0,0,0,0}, f32x4{0,0,0,0}, f32x4{0,0,0,0}};
        #pragma unroll
        for (int kt = 0; kt < 32; ++kt) {
            bf16x8 bh = *(const bf16x8*)(wbase + kt * 512);
            bf16x8 bl = wlo[kt];
            const int koff = kt * 32;
            #pragma unroll
            for (int m = 0; m < 4; ++m) {
                bf16x8 ah = *(const bf16x8*)(ahp + (size_t)m * 16 * DDIM + koff);
                bf16x8 al = *(const bf16x8*)(alp + (size_t)m * 16 * DDIM + koff);
                acc[m] = __builtin_amdgcn_mfma_f32_16x16x32_bf16(ah, bh, acc[m], 0, 0, 0);
                acc[m] = __builtin_amdgcn_mfma_f32_16x16x32_bf16(al, bh, acc[m], 0, 0, 0);
                acc[m] = __builtin_amdgcn_mfma_f32_16x16x32_bf16(ah, bl, acc[m], 0, 0, 0);
            }
        }
        epilogue(t, acc, dh, dl);
        if (t < TSTEPS - 1) barrier(t);
    }
}

extern "C" void kernel_launch(void* const* d_in, const int* in_sizes, int n_in,
                              void* d_out, int out_size, void* d_ws, size_t ws_size,
                              hipStream_t stream) {
    const float* x = (const float*)d_in[0];
    const float* W = (const float*)d_in[1];
    const float* U = (const float*)d_in[2];
    const float* b = (const float*)d_in[3];
    float* out = (float*)d_out;

    // ws layout: 2 MB state (2 bufs x [hi 512KB | lo 512KB]) + 32 KB sync counters
    unsigned short* hb = (unsigned short*)d_ws;
    int* syncc = (int*)((char*)d_ws + (2u << 20));

    hipMemsetAsync(syncc, 0, 8192 * sizeof(int), stream);

    void* kargs[] = { (void*)&x, (void*)&W, (void*)&U, (void*)&b,
                      (void*)&out, (void*)&hb, (void*)&syncc };
    // 256 blocks (1/CU), 148480 B dynamic LDS (128 KB weights-hi + 17 KB gate buf)
    hipLaunchCooperativeKernel((const void*)gru_persistent, dim3(256), dim3(256),
                               kargs, 148480, stream);
}